// Round 7
// baseline (282.034 us; speedup 1.0000x reference)
//
#include <hip/hip_runtime.h>
#include <math.h>

typedef __attribute__((ext_vector_type(4))) float f32x4;
typedef __attribute__((ext_vector_type(2))) long lng2;

#define NCLS   50000
#define KSUB   3
#define DIM    512            // elements; fp8 row = 512 B, f32 row = 2 KB
#define NROWSW (NCLS*KSUB)    // 150000
#define BQ     1024

#define SCALEF 30.0f
#define EPSC   1e-7f
#define COSM   0.8775825618903728f
#define SINM   0.4794255386042030f

#define BN     48             // weight rows per tile (lcm(16,3))
#define TW     3              // 16-row MFMA tiles
#define NJ     2              // 16-col B subtiles per wave (32 cols/wave, 256/block)
#define NTILES (NROWSW/BN)    // 3125
#define NRG    64             // row groups
#define NCG    4              // col groups of 256; partners (same rg) share an XCD
#define TILEB  (BN*DIM)       // 24576 B per LDS buffer (fp8)

__device__ __forceinline__ float wave_sum(float v) {
#pragma unroll
  for (int m = 1; m < 64; m <<= 1) v += __shfl_xor(v, m, 64);
  return v;
}

__device__ __forceinline__ unsigned pack4_fp8(float a, float b, float c, float d) {
  int v = 0;
  v = __builtin_amdgcn_cvt_pk_fp8_f32(a, b, v, false);
  v = __builtin_amdgcn_cvt_pk_fp8_f32(c, d, v, true);
  return (unsigned)v;
}

__device__ __forceinline__ float eterm(float v) {
  v = fminf(fmaxf(v, -1.f + EPSC), 1.f - EPSC);
  return __expf(SCALEF * v);
}

// K0: normalize embeddings, store fp8 e4m3 [1024][512]
__global__ __launch_bounds__(64) void k_norm_e(const float* __restrict__ E,
                                               unsigned char* __restrict__ En8) {
  const int b = blockIdx.x, l = threadIdx.x;
  const float4* p = reinterpret_cast<const float4*>(E + (size_t)b * DIM + l * 8);
  float4 a = p[0], c = p[1];
  float ss = a.x*a.x + a.y*a.y + a.z*a.z + a.w*a.w
           + c.x*c.x + c.y*c.y + c.z*c.z + c.w*c.w;
  ss = wave_sum(ss);
  float inv = rsqrtf(ss);
  uint2 o;
  o.x = pack4_fp8(a.x*inv, a.y*inv, a.z*inv, a.w*inv);
  o.y = pack4_fp8(c.x*inv, c.y*inv, c.z*inv, c.w*inv);
  *reinterpret_cast<uint2*>(En8 + (size_t)b * DIM + l * 8) = o;
}

// K2: exact f32 target-class cosine + margin terms (verified)
__global__ __launch_bounds__(64) void k_target(const float* __restrict__ E,
                                               const int* __restrict__ lab,
                                               const float* __restrict__ W,
                                               float* __restrict__ delta,
                                               float* __restrict__ tl) {
  const int b = blockIdx.x, l = threadIdx.x;
  const float4* pe = reinterpret_cast<const float4*>(E + (size_t)b * DIM + l * 8);
  float4 e0 = pe[0], e1 = pe[1];
  float es = e0.x*e0.x + e0.y*e0.y + e0.z*e0.z + e0.w*e0.w
           + e1.x*e1.x + e1.y*e1.y + e1.z*e1.z + e1.w*e1.w;
  es = wave_sum(es);
  const int L = lab[b];
  float mx = -2.f;
#pragma unroll
  for (int k = 0; k < KSUB; ++k) {
    const float4* pw = reinterpret_cast<const float4*>(W + (size_t)(L * KSUB + k) * DIM + l * 8);
    float4 w0 = pw[0], w1 = pw[1];
    float ds = e0.x*w0.x + e0.y*w0.y + e0.z*w0.z + e0.w*w0.w
             + e1.x*w1.x + e1.y*w1.y + e1.z*w1.z + e1.w*w1.w;
    float ws = w0.x*w0.x + w0.y*w0.y + w0.z*w0.z + w0.w*w0.w
             + w1.x*w1.x + w1.y*w1.y + w1.z*w1.z + w1.w*w1.w;
    ds = wave_sum(ds);
    ws = wave_sum(ws);
    float ck = ds * rsqrtf(es * ws);
    mx = fmaxf(mx, ck);
  }
  if (l == 0) {
    float cc = fminf(fmaxf(mx, -1.f + EPSC), 1.f - EPSC);
    float sn = sqrtf(fmaxf(1.f - cc * cc, 0.f));
    float mg = cc * COSM - sn * SINM;           // cos(arccos(cc)+m)
    delta[b] = __expf(SCALEF * mg) - __expf(SCALEF * cc);
    tl[b]    = SCALEF * mg;
  }
}

// K1: fused normalize+GEMM. E-fragments in registers (64 VGPR/wave, loaded once);
// W read as raw f32, normalized in-register, packed fp8, ds_written into dbuf LDS
// in PAIRED-HALVES layout: lane l's 8 B of row r -> chunk ((l>>3)*4+(l&3)) ^ (r&15),
// half (l>>2)&1. Compute side: ONE ds_read_b128 per (t,ks2) yields both MFMA
// K-halves. T14 split: stage-loads issued before compute, finish after.
__global__ __launch_bounds__(512, 1) void k_main(const float* __restrict__ W,
                                                 const unsigned char* __restrict__ En8,
                                                 float* __restrict__ Zp) {
  __shared__ __align__(16) unsigned char wlds[2 * TILEB];   // 48 KB
  const int tid  = threadIdx.x;
  const int lane = tid & 63;
  const int wv   = tid >> 6;
  const int g    = lane >> 4;
  const int c    = lane & 15;
  const int rg   = blockIdx.x & (NRG - 1);   // partners share XCD: blk%8 = rg%8
  const int cg   = blockIdx.x >> 6;

  const int pch  = (lane >> 3) * 4 + (lane & 3);   // paired-halves chunk of this lane
  const int phh  = (lane >> 2) & 1;                // half within chunk

  // ---- load this wave's E fragments once: 2 x 16 longs = 64 VGPRs ----
  long bfr[NJ][16];
#pragma unroll
  for (int j = 0; j < NJ; ++j) {
    const int col = cg * 256 + wv * 32 + j * 16 + c;
#pragma unroll
    for (int ks = 0; ks < 16; ++ks)
      bfr[j][ks] = *reinterpret_cast<const long*>(
          En8 + (size_t)col * DIM + ks * 32 + g * 8);
  }

  float zreg[NJ];
#pragma unroll
  for (int j = 0; j < NJ; ++j) zreg[j] = 0.f;

  // ---- prologue: stage tile rg into buffer 0 ----
  {
    const float* Wt = W + (size_t)rg * BN * DIM;
#pragma unroll
    for (int i = 0; i < 6; ++i) {
      const int r = wv * 6 + i;
      const float4* p = reinterpret_cast<const float4*>(Wt + (size_t)r * DIM + lane * 8);
      float4 a = p[0], b = p[1];
      float ss = a.x*a.x + a.y*a.y + a.z*a.z + a.w*a.w
               + b.x*b.x + b.y*b.y + b.z*b.z + b.w*b.w;
      ss = wave_sum(ss);
      float inv = rsqrtf(ss);
      uint2 o;
      o.x = pack4_fp8(a.x*inv, a.y*inv, a.z*inv, a.w*inv);
      o.y = pack4_fp8(b.x*inv, b.y*inv, b.z*inv, b.w*inv);
      *reinterpret_cast<uint2*>(wlds + r * DIM + (((pch ^ (r & 15)) << 4) + phh * 8)) = o;
    }
  }
  __syncthreads();
  int cur = 0;

  for (int tile = rg; tile < NTILES; tile += NRG) {
    const int nxt = tile + NRG;

    // ---- T14 issue-early: load next tile's 6 rows (f32) into registers ----
    float4 sa[6], sb[6];
    if (nxt < NTILES) {
      const float* Wt = W + (size_t)nxt * BN * DIM;
#pragma unroll
      for (int i = 0; i < 6; ++i) {
        const float4* p = reinterpret_cast<const float4*>(
            Wt + (size_t)(wv * 6 + i) * DIM + lane * 8);
        sa[i] = p[0];
        sb[i] = p[1];
      }
    }

    // ---- compute current buffer ----
    const unsigned char* lbuf = wlds + cur * TILEB;
    f32x4 acc[TW][NJ];
#pragma unroll
    for (int t = 0; t < TW; ++t)
#pragma unroll
      for (int j = 0; j < NJ; ++j) acc[t][j] = (f32x4){0.f, 0.f, 0.f, 0.f};

#pragma unroll
    for (int ks2 = 0; ks2 < 8; ++ks2) {
#pragma unroll
      for (int t = 0; t < TW; ++t) {
        const int r = t * 16 + c;
        lng2 v = *reinterpret_cast<const lng2*>(
            lbuf + r * DIM + (((ks2 * 4 + g) ^ (r & 15)) << 4));
        const long a0 = v[0], a1 = v[1];
#pragma unroll
        for (int j = 0; j < NJ; ++j) {
          acc[t][j] = __builtin_amdgcn_mfma_f32_16x16x32_fp8_fp8(
              a0, bfr[j][2 * ks2], acc[t][j], 0, 0, 0);
          acc[t][j] = __builtin_amdgcn_mfma_f32_16x16x32_fp8_fp8(
              a1, bfr[j][2 * ks2 + 1], acc[t][j], 0, 0, 0);
        }
      }
    }

    // ---- epilogue: max over sub-center triples (verified), exp, per-col sums ----
#pragma unroll
    for (int j = 0; j < NJ; ++j) {
      float zc = 0.f;
#pragma unroll
      for (int t = 0; t < TW; ++t) {
        float s0, s1;
        if (t + 1 < TW) {
          s0 = (g == 0) ? acc[t + 1][j][0] : acc[t][j][0];
          s1 = (g == 0) ? acc[t + 1][j][1] : acc[t][j][1];
        } else {
          s0 = (g == 0) ? -2.f : acc[t][j][0];
          s1 = (g == 0) ? -2.f : acc[t][j][1];
        }
        float e0 = __shfl(s0, (lane + 16) & 63, 64);
        float e1 = __shfl(s1, (lane + 16) & 63, 64);
        const int m = (4 * t + g) % 3;
        float a0 = acc[t][j][0], a1 = acc[t][j][1], a2 = acc[t][j][2], a3 = acc[t][j][3];
        if (m == 0)      zc += eterm(fmaxf(fmaxf(a0, a1), a2)) + eterm(fmaxf(fmaxf(a3, e0), e1));
        else if (m == 1) zc += eterm(fmaxf(fmaxf(a2, a3), e0));
        else             zc += eterm(fmaxf(fmaxf(a1, a2), a3));
      }
      zc += __shfl_xor(zc, 16, 64);
      zc += __shfl_xor(zc, 32, 64);
      zreg[j] += zc;
    }

    // ---- T14 finish-late: normalize, pack fp8, swizzled ds_write to buf^1 ----
    if (nxt < NTILES) {
      unsigned char* nbuf = wlds + (cur ^ 1) * TILEB;
#pragma unroll
      for (int i = 0; i < 6; ++i) {
        const int r = wv * 6 + i;
        float4 a = sa[i], b = sb[i];
        float ss = a.x*a.x + a.y*a.y + a.z*a.z + a.w*a.w
                 + b.x*b.x + b.y*b.y + b.z*b.z + b.w*b.w;
        ss = wave_sum(ss);
        float inv = rsqrtf(ss);
        uint2 o;
        o.x = pack4_fp8(a.x*inv, a.y*inv, a.z*inv, a.w*inv);
        o.y = pack4_fp8(b.x*inv, b.y*inv, b.z*inv, b.w*inv);
        *reinterpret_cast<uint2*>(nbuf + r * DIM + (((pch ^ (r & 15)) << 4) + phh * 8)) = o;
      }
    }

    __syncthreads();   // staging visible to all waves + all done with cur
    cur ^= 1;
  }

  if (g == 0) {
#pragma unroll
    for (int j = 0; j < NJ; ++j)
      Zp[(size_t)rg * BQ + cg * 256 + wv * 32 + j * 16 + c] = zreg[j];
  }
}

// K3: Z[b] = sum over 64 row-group partials; per-row loss; block partial sums
__global__ __launch_bounds__(256) void k_reduce(const float* __restrict__ Zp,
                                                const float* __restrict__ delta,
                                                const float* __restrict__ tl,
                                                float* __restrict__ part) {
  const int b = blockIdx.x * 256 + threadIdx.x;
  float z = 0.f;
#pragma unroll 8
  for (int nb = 0; nb < NRG; ++nb) z += Zp[(size_t)nb * BQ + b];
  float lossb = logf(z + delta[b]) - tl[b];
  __shared__ float sm[256];
  sm[threadIdx.x] = lossb;
  __syncthreads();
#pragma unroll
  for (int s = 128; s > 0; s >>= 1) {
    if (threadIdx.x < s) sm[threadIdx.x] += sm[threadIdx.x + s];
    __syncthreads();
  }
  if (threadIdx.x == 0) part[blockIdx.x] = sm[0];
}

__global__ void k_final(const float* __restrict__ part, float* __restrict__ out) {
  out[0] = (part[0] + part[1] + part[2] + part[3]) * (1.0f / BQ);
}

extern "C" void kernel_launch(void* const* d_in, const int* in_sizes, int n_in,
                              void* d_out, int out_size, void* d_ws, size_t ws_size,
                              hipStream_t stream) {
  const float* E  = (const float*)d_in[0];
  const int* lab  = (const int*)d_in[1];
  const float* W  = (const float*)d_in[2];

  char* ws = (char*)d_ws;
  unsigned char* En8 = (unsigned char*)ws;                          // 512 KB
  float* Zp    = (float*)(ws + (size_t)BQ * DIM);                   // 64*1024*4 = 256 KB
  float* delta = Zp + (size_t)NRG * BQ;
  float* tl    = delta + BQ;
  float* part  = tl + BQ;

  hipLaunchKernelGGL(k_norm_e, dim3(BQ),        dim3(64),  0, stream, E, En8);
  hipLaunchKernelGGL(k_target, dim3(BQ),        dim3(64),  0, stream, E, lab, W, delta, tl);
  hipLaunchKernelGGL(k_main,   dim3(NRG * NCG), dim3(512), 0, stream, W, En8, Zp);
  hipLaunchKernelGGL(k_reduce, dim3(4),         dim3(256), 0, stream, Zp, delta, tl, part);
  hipLaunchKernelGGL(k_final,  dim3(1),         dim3(1),   0, stream, part, (float*)d_out);
}

// Round 8
// 219.386 us; speedup vs baseline: 1.2856x; 1.2856x over previous
//
#include <hip/hip_runtime.h>
#include <math.h>

typedef __attribute__((ext_vector_type(4))) float f32x4;
typedef __attribute__((ext_vector_type(2))) long lng2;

#define NCLS   50000
#define KSUB   3
#define DIM    512            // elements; fp8 row = 512 B, f32 row = 2 KB
#define NROWSW (NCLS*KSUB)    // 150000
#define BQ     1024

#define SCALEF 30.0f
#define EPSC   1e-7f
#define COSM   0.8775825618903728f
#define SINM   0.4794255386042030f

#define BN     48             // weight rows per tile (lcm(16,3))
#define TW     3              // 16-row MFMA tiles
#define NJ     4              // 16-col B subtiles per wave (64 cols/wave, 512/block)
#define NTILES (NROWSW/BN)    // 3125
#define NRG    128            // row groups (tiles strided by 128)
#define NCG    2              // col groups of 512; partners (same rg) share an XCD
#define TILEB  (BN*DIM)       // 24576 B per LDS buffer (fp8)

__device__ __forceinline__ float wave_sum(float v) {
#pragma unroll
  for (int m = 1; m < 64; m <<= 1) v += __shfl_xor(v, m, 64);
  return v;
}

__device__ __forceinline__ unsigned pack4_fp8(float a, float b, float c, float d) {
  int v = 0;
  v = __builtin_amdgcn_cvt_pk_fp8_f32(a, b, v, false);
  v = __builtin_amdgcn_cvt_pk_fp8_f32(c, d, v, true);
  return (unsigned)v;
}

__device__ __forceinline__ float eterm(float v) {
  v = fminf(fmaxf(v, -1.f + EPSC), 1.f - EPSC);
  return __expf(SCALEF * v);
}

// K-pre: normalize weight rows, store fp8 e4m3 in PAIRED-HALVES row format:
// logical 8B piece of lane l (K bytes [l*8, l*8+8)) goes to
// row*512 + ((l>>3)*4 + (l&3))*16 + ((l>>2)&1)*8.  So 16B chunk p = kp*4+g
// holds K-halves (2kp, 2kp+1) of A-group g -> one ds_read_b128 feeds 2 MFMAs.
__global__ __launch_bounds__(256) void k_prenorm(const float* __restrict__ W,
                                                 unsigned char* __restrict__ Wn8) {
  const int row = blockIdx.x * 4 + (threadIdx.x >> 6);
  const int l = threadIdx.x & 63;
  const float4* p = reinterpret_cast<const float4*>(W + (size_t)row * DIM + l * 8);
  float4 a = p[0], d = p[1];
  float ss = a.x*a.x + a.y*a.y + a.z*a.z + a.w*a.w
           + d.x*d.x + d.y*d.y + d.z*d.z + d.w*d.w;
  ss = wave_sum(ss);
  float inv = rsqrtf(ss);
  uint2 o;
  o.x = pack4_fp8(a.x*inv, a.y*inv, a.z*inv, a.w*inv);
  o.y = pack4_fp8(d.x*inv, d.y*inv, d.z*inv, d.w*inv);
  long v; memcpy(&v, &o, 8);
  *reinterpret_cast<long*>(Wn8 + (size_t)row * DIM +
                           (((l >> 3) * 4 + (l & 3)) << 4) + ((l >> 2) & 1) * 8) = v;
}

// K-prep: normalize embeddings -> fp8 En8 (linear layout) AND exact f32
// target-class margin terms (reuses |e|^2). One wave per batch row.
__global__ __launch_bounds__(64) void k_prep(const float* __restrict__ E,
                                             const int* __restrict__ lab,
                                             const float* __restrict__ W,
                                             unsigned char* __restrict__ En8,
                                             float* __restrict__ delta,
                                             float* __restrict__ tl) {
  const int b = blockIdx.x, l = threadIdx.x;
  const float4* pe = reinterpret_cast<const float4*>(E + (size_t)b * DIM + l * 8);
  float4 e0 = pe[0], e1 = pe[1];
  float es = e0.x*e0.x + e0.y*e0.y + e0.z*e0.z + e0.w*e0.w
           + e1.x*e1.x + e1.y*e1.y + e1.z*e1.z + e1.w*e1.w;
  es = wave_sum(es);
  const float inv = rsqrtf(es);
  uint2 o;
  o.x = pack4_fp8(e0.x*inv, e0.y*inv, e0.z*inv, e0.w*inv);
  o.y = pack4_fp8(e1.x*inv, e1.y*inv, e1.z*inv, e1.w*inv);
  *reinterpret_cast<uint2*>(En8 + (size_t)b * DIM + l * 8) = o;

  const int L = lab[b];
  float mx = -2.f;
#pragma unroll
  for (int k = 0; k < KSUB; ++k) {
    const float4* pw = reinterpret_cast<const float4*>(W + (size_t)(L * KSUB + k) * DIM + l * 8);
    float4 w0 = pw[0], w1 = pw[1];
    float ds = e0.x*w0.x + e0.y*w0.y + e0.z*w0.z + e0.w*w0.w
             + e1.x*w1.x + e1.y*w1.y + e1.z*w1.z + e1.w*w1.w;
    float ws = w0.x*w0.x + w0.y*w0.y + w0.z*w0.z + w0.w*w0.w
             + w1.x*w1.x + w1.y*w1.y + w1.z*w1.z + w1.w*w1.w;
    ds = wave_sum(ds);
    ws = wave_sum(ws);
    float ck = ds * rsqrtf(es * ws);
    mx = fmaxf(mx, ck);
  }
  if (l == 0) {
    float cc = fminf(fmaxf(mx, -1.f + EPSC), 1.f - EPSC);
    float sn = sqrtf(fmaxf(1.f - cc * cc, 0.f));
    float mg = cc * COSM - sn * SINM;           // cos(arccos(cc)+m)
    delta[b] = __expf(SCALEF * mg) - __expf(SCALEF * cc);
    tl[b]    = SCALEF * mg;
  }
}

// stage one 48-row paired-format tile (24 KB) via global_load_lds.
// LDS chunk m of row r <- Wn8 paired-chunk (m ^ (r&15)); read side XORs the
// same mask -> verified-0-conflict layout (R7 measured).
__device__ __forceinline__ void stage_tile(const unsigned char* __restrict__ Wt,
                                           unsigned char* lbuf, int wv, int lane) {
#pragma unroll
  for (int i = 0; i < 3; ++i) {
    const int rlo = wv * 2 + (lane >> 5);          // r & 15
    const int r = i * 16 + rlo;
    const int m = (lane & 31) ^ rlo;
    const unsigned char* src = Wt + (size_t)r * DIM + m * 16;
    __builtin_amdgcn_global_load_lds(
        (const __attribute__((address_space(1))) unsigned int*)src,
        (__attribute__((address_space(3))) unsigned int*)(lbuf + (i * 16 + wv * 2) * DIM),
        16, 0, 0);
  }
}

// K1: E-fragments in registers (NJ=4: 128 VGPR/wave, loaded once); W tiles in
// dbuf LDS via global_load_lds; one ds_read_b128 per (t,ks2) feeds 2 MFMAs.
// Block (rg, cg): tiles rg, rg+128, ...; cols cg*512 .. +512.
__global__ __launch_bounds__(512, 1) void k_main(const unsigned char* __restrict__ Wn8,
                                                 const unsigned char* __restrict__ En8,
                                                 float* __restrict__ Zp) {
  __shared__ __align__(16) unsigned char wlds[2 * TILEB];   // 48 KB
  const int tid  = threadIdx.x;
  const int lane = tid & 63;
  const int wv   = tid >> 6;
  const int g    = lane >> 4;
  const int c    = lane & 15;
  const int rg   = blockIdx.x & (NRG - 1);   // partners share XCD: blk%8 = rg%8
  const int cg   = blockIdx.x >> 7;

  // ---- load this wave's E fragments once: 4 x 16 longs = 128 VGPRs ----
  long bfr[NJ][16];
#pragma unroll
  for (int j = 0; j < NJ; ++j) {
    const int col = cg * 512 + wv * 64 + j * 16 + c;
#pragma unroll
    for (int ks = 0; ks < 16; ++ks)
      bfr[j][ks] = *reinterpret_cast<const long*>(
          En8 + (size_t)col * DIM + ks * 32 + g * 8);
  }

  float zreg[NJ];
#pragma unroll
  for (int j = 0; j < NJ; ++j) zreg[j] = 0.f;

  stage_tile(Wn8 + (size_t)rg * TILEB, wlds, wv, lane);
  __syncthreads();
  int cur = 0;

  for (int tile = rg; tile < NTILES; tile += NRG) {
    const int nxt = tile + NRG;
    if (nxt < NTILES)
      stage_tile(Wn8 + (size_t)nxt * TILEB, wlds + (cur ^ 1) * TILEB, wv, lane);

    const unsigned char* lbuf = wlds + cur * TILEB;

    f32x4 acc[TW][NJ];
#pragma unroll
    for (int t = 0; t < TW; ++t)
#pragma unroll
      for (int j = 0; j < NJ; ++j) acc[t][j] = (f32x4){0.f, 0.f, 0.f, 0.f};

#pragma unroll
    for (int ks2 = 0; ks2 < 8; ++ks2) {
#pragma unroll
      for (int t = 0; t < TW; ++t) {
        const int r = t * 16 + c;
        lng2 v = *reinterpret_cast<const lng2*>(
            lbuf + r * DIM + (((ks2 * 4 + g) ^ c) << 4));
        const long a0 = v[0], a1 = v[1];
#pragma unroll
        for (int j = 0; j < NJ; ++j) {
          acc[t][j] = __builtin_amdgcn_mfma_f32_16x16x32_fp8_fp8(
              a0, bfr[j][2 * ks2], acc[t][j], 0, 0, 0);
          acc[t][j] = __builtin_amdgcn_mfma_f32_16x16x32_fp8_fp8(
              a1, bfr[j][2 * ks2 + 1], acc[t][j], 0, 0, 0);
        }
      }
    }

    // ---- epilogue: max over sub-center triples (verified), exp, per-col sums ----
#pragma unroll
    for (int j = 0; j < NJ; ++j) {
      float zc = 0.f;
#pragma unroll
      for (int t = 0; t < TW; ++t) {
        float s0, s1;
        if (t + 1 < TW) {
          s0 = (g == 0) ? acc[t + 1][j][0] : acc[t][j][0];
          s1 = (g == 0) ? acc[t + 1][j][1] : acc[t][j][1];
        } else {
          s0 = (g == 0) ? -2.f : acc[t][j][0];
          s1 = (g == 0) ? -2.f : acc[t][j][1];
        }
        float e0 = __shfl(s0, (lane + 16) & 63, 64);
        float e1 = __shfl(s1, (lane + 16) & 63, 64);
        const int m = (4 * t + g) % 3;
        float a0 = acc[t][j][0], a1 = acc[t][j][1], a2 = acc[t][j][2], a3 = acc[t][j][3];
        if (m == 0)      zc += eterm(fmaxf(fmaxf(a0, a1), a2)) + eterm(fmaxf(fmaxf(a3, e0), e1));
        else if (m == 1) zc += eterm(fmaxf(fmaxf(a2, a3), e0));
        else             zc += eterm(fmaxf(fmaxf(a1, a2), a3));
      }
      zc += __shfl_xor(zc, 16, 64);
      zc += __shfl_xor(zc, 32, 64);
      zreg[j] += zc;
    }

    __syncthreads();   // staging drained + all waves done with cur
    cur ^= 1;
  }

  if (g == 0) {
#pragma unroll
    for (int j = 0; j < NJ; ++j)
      Zp[(size_t)rg * BQ + cg * 512 + wv * 64 + j * 16 + c] = zreg[j];
  }
}

// K3: Z[b] = sum over 128 row-group partials; per-row loss; block partial sums
__global__ __launch_bounds__(256) void k_reduce(const float* __restrict__ Zp,
                                                const float* __restrict__ delta,
                                                const float* __restrict__ tl,
                                                float* __restrict__ part) {
  const int b = blockIdx.x * 256 + threadIdx.x;
  float z = 0.f;
#pragma unroll 8
  for (int nb = 0; nb < NRG; ++nb) z += Zp[(size_t)nb * BQ + b];
  float lossb = logf(z + delta[b]) - tl[b];
  __shared__ float sm[256];
  sm[threadIdx.x] = lossb;
  __syncthreads();
#pragma unroll
  for (int s = 128; s > 0; s >>= 1) {
    if (threadIdx.x < s) sm[threadIdx.x] += sm[threadIdx.x + s];
    __syncthreads();
  }
  if (threadIdx.x == 0) part[blockIdx.x] = sm[0];
}

__global__ void k_final(const float* __restrict__ part, float* __restrict__ out) {
  out[0] = (part[0] + part[1] + part[2] + part[3]) * (1.0f / BQ);
}

extern "C" void kernel_launch(void* const* d_in, const int* in_sizes, int n_in,
                              void* d_out, int out_size, void* d_ws, size_t ws_size,
                              hipStream_t stream) {
  const float* E  = (const float*)d_in[0];
  const int* lab  = (const int*)d_in[1];
  const float* W  = (const float*)d_in[2];

  char* ws = (char*)d_ws;
  unsigned char* En8 = (unsigned char*)ws;                          // 512 KB
  unsigned char* Wn8 = (unsigned char*)(ws + (size_t)BQ * DIM);     // 76.8 MB
  char* after = ws + (size_t)BQ * DIM + (size_t)NROWSW * DIM;
  float* Zp    = (float*)after;                                     // 128*1024*4 = 512 KB
  float* delta = Zp + (size_t)NRG * BQ;
  float* tl    = delta + BQ;
  float* part  = tl + BQ;

  hipLaunchKernelGGL(k_prenorm, dim3(NROWSW / 4), dim3(256), 0, stream, W, Wn8);
  hipLaunchKernelGGL(k_prep,    dim3(BQ),         dim3(64),  0, stream, E, lab, W, En8, delta, tl);
  hipLaunchKernelGGL(k_main,    dim3(NRG * NCG),  dim3(512), 0, stream, Wn8, En8, Zp);
  hipLaunchKernelGGL(k_reduce,  dim3(4),          dim3(256), 0, stream, Zp, delta, tl, part);
  hipLaunchKernelGGL(k_final,   dim3(1),          dim3(1),   0, stream, part, (float*)d_out);
}

// Round 9
// 160.016 us; speedup vs baseline: 1.7625x; 1.3710x over previous
//
#include <hip/hip_runtime.h>
#include <math.h>

typedef __attribute__((ext_vector_type(4))) float f32x4;
typedef __attribute__((ext_vector_type(8))) int  i32x8;

#define NCLS   50000
#define KSUB   3
#define DIM    512            // elements; fp8 row = 512 B, f32 row = 2 KB
#define NROWSW (NCLS*KSUB)    // 150000
#define BQ     1024

#define SCALEF 30.0f
#define EPSC   1e-7f
#define COSM   0.8775825618903728f
#define SINM   0.4794255386042030f

#define BN     48             // weight rows per tile (lcm(16,3))
#define TW     3              // 16-row MFMA tiles
#define NJ     2              // 16-col B subtiles per wave (32 cols/wave, 256/block)
#define NKQ    4              // K=512 / 128 per scaled MFMA
#define NTILES (NROWSW/BN)    // 3125
#define NRG    128            // row groups
#define NCG    4              // col groups of 256; partners (same rg) share an XCD
#define TILEB  (BN*DIM)       // 24576 B per LDS buffer (fp8)
#define SCL1   0x7F7F7F7F     // E8M0 scale = 1.0 in every byte

__device__ __forceinline__ float wave_sum(float v) {
#pragma unroll
  for (int m = 1; m < 64; m <<= 1) v += __shfl_xor(v, m, 64);
  return v;
}

__device__ __forceinline__ unsigned pack4_fp8(float a, float b, float c, float d) {
  int v = 0;
  v = __builtin_amdgcn_cvt_pk_fp8_f32(a, b, v, false);
  v = __builtin_amdgcn_cvt_pk_fp8_f32(c, d, v, true);
  return (unsigned)v;
}

__device__ __forceinline__ float eterm(float v) {
  v = fminf(fmaxf(v, -1.f + EPSC), 1.f - EPSC);
  return __expf(SCALEF * v);
}

// K-pre: normalize weight rows, store fp8 e4m3 [150000][512] natural order
__global__ __launch_bounds__(256) void k_prenorm(const float* __restrict__ W,
                                                 unsigned char* __restrict__ Wn8) {
  const int row = blockIdx.x * 4 + (threadIdx.x >> 6);
  const int l = threadIdx.x & 63;
  const float4* p = reinterpret_cast<const float4*>(W + (size_t)row * DIM + l * 8);
  float4 a = p[0], d = p[1];
  float ss = a.x*a.x + a.y*a.y + a.z*a.z + a.w*a.w
           + d.x*d.x + d.y*d.y + d.z*d.z + d.w*d.w;
  ss = wave_sum(ss);
  float inv = rsqrtf(ss);
  uint2 o;
  o.x = pack4_fp8(a.x*inv, a.y*inv, a.z*inv, a.w*inv);
  o.y = pack4_fp8(d.x*inv, d.y*inv, d.z*inv, d.w*inv);
  *reinterpret_cast<uint2*>(Wn8 + (size_t)row * DIM + l * 8) = o;
}

// K-prep: normalize embeddings -> fp8 En8 (natural) AND exact f32 target-class
// margin terms (reuses |e|^2). One wave per batch row.
__global__ __launch_bounds__(64) void k_prep(const float* __restrict__ E,
                                             const int* __restrict__ lab,
                                             const float* __restrict__ W,
                                             unsigned char* __restrict__ En8,
                                             float* __restrict__ delta,
                                             float* __restrict__ tl) {
  const int b = blockIdx.x, l = threadIdx.x;
  const float4* pe = reinterpret_cast<const float4*>(E + (size_t)b * DIM + l * 8);
  float4 e0 = pe[0], e1 = pe[1];
  float es = e0.x*e0.x + e0.y*e0.y + e0.z*e0.z + e0.w*e0.w
           + e1.x*e1.x + e1.y*e1.y + e1.z*e1.z + e1.w*e1.w;
  es = wave_sum(es);
  const float inv = rsqrtf(es);
  uint2 o;
  o.x = pack4_fp8(e0.x*inv, e0.y*inv, e0.z*inv, e0.w*inv);
  o.y = pack4_fp8(e1.x*inv, e1.y*inv, e1.z*inv, e1.w*inv);
  *reinterpret_cast<uint2*>(En8 + (size_t)b * DIM + l * 8) = o;

  const int L = lab[b];
  float mx = -2.f;
#pragma unroll
  for (int k = 0; k < KSUB; ++k) {
    const float4* pw = reinterpret_cast<const float4*>(W + (size_t)(L * KSUB + k) * DIM + l * 8);
    float4 w0 = pw[0], w1 = pw[1];
    float ds = e0.x*w0.x + e0.y*w0.y + e0.z*w0.z + e0.w*w0.w
             + e1.x*w1.x + e1.y*w1.y + e1.z*w1.z + e1.w*w1.w;
    float ws = w0.x*w0.x + w0.y*w0.y + w0.z*w0.z + w0.w*w0.w
             + w1.x*w1.x + w1.y*w1.y + w1.z*w1.z + w1.w*w1.w;
    ds = wave_sum(ds);
    ws = wave_sum(ws);
    float ck = ds * rsqrtf(es * ws);
    mx = fmaxf(mx, ck);
  }
  if (l == 0) {
    float cc = fminf(fmaxf(mx, -1.f + EPSC), 1.f - EPSC);
    float sn = sqrtf(fmaxf(1.f - cc * cc, 0.f));
    float mg = cc * COSM - sn * SINM;           // cos(arccos(cc)+m)
    delta[b] = __expf(SCALEF * mg) - __expf(SCALEF * cc);
    tl[b]    = SCALEF * mg;
  }
}

// stage one 48-row natural-order tile (24 KB) via global_load_lds.
// LDS slot s of row r holds global chunk s ^ (r&15); involution, read side XORs same.
__device__ __forceinline__ void stage_tile(const unsigned char* __restrict__ Wt,
                                           unsigned char* lbuf, int wv, int lane) {
#pragma unroll
  for (int i = 0; i < 3; ++i) {
    const int rlo = wv * 2 + (lane >> 5);          // = r & 15
    const int r = i * 16 + rlo;
    const int m = (lane & 31) ^ rlo;
    const unsigned char* src = Wt + (size_t)r * DIM + m * 16;
    __builtin_amdgcn_global_load_lds(
        (const __attribute__((address_space(1))) unsigned int*)src,
        (__attribute__((address_space(3))) unsigned int*)(lbuf + (i * 16 + wv * 2) * DIM),
        16, 0, 0);
  }
}

// K1: MX-scaled fp8 GEMM (scales=1.0). E-fragments in registers (NJ=2: 64 VGPR,
// loaded once, natural 32B blocks); W tiles in dbuf LDS via global_load_lds.
// 4 waves/SIMD (2 blocks/CU). A and B both fed with identical natural
// (lane,byte)->K maps, so operand-layout permutations cancel.
__global__ __launch_bounds__(512, 4) void k_main(const unsigned char* __restrict__ Wn8,
                                                 const unsigned char* __restrict__ En8,
                                                 float* __restrict__ Zp) {
  __shared__ __align__(16) unsigned char wlds[2 * TILEB];   // 48 KB
  const int tid  = threadIdx.x;
  const int lane = tid & 63;
  const int wv   = tid >> 6;
  const int g    = lane >> 4;
  const int c    = lane & 15;
  const int rg   = blockIdx.x & (NRG - 1);   // partners share XCD: blk%8 = rg%8
  const int cg   = blockIdx.x >> 7;

  // ---- load this wave's E fragments once: 2 x 4 x i32x8 = 64 VGPRs ----
  i32x8 bfr[NJ][NKQ];
#pragma unroll
  for (int j = 0; j < NJ; ++j) {
    const int col = cg * 256 + wv * 32 + j * 16 + c;
#pragma unroll
    for (int kq = 0; kq < NKQ; ++kq)
      bfr[j][kq] = *reinterpret_cast<const i32x8*>(
          En8 + (size_t)col * DIM + kq * 128 + g * 32);
  }

  float zreg[NJ];
#pragma unroll
  for (int j = 0; j < NJ; ++j) zreg[j] = 0.f;

  stage_tile(Wn8 + (size_t)rg * TILEB, wlds, wv, lane);
  __syncthreads();
  int cur = 0;

  for (int tile = rg; tile < NTILES; tile += NRG) {
    const int nxt = tile + NRG;
    if (nxt < NTILES)
      stage_tile(Wn8 + (size_t)nxt * TILEB, wlds + (cur ^ 1) * TILEB, wv, lane);

    const unsigned char* lbuf = wlds + cur * TILEB;

    f32x4 acc[TW][NJ];
#pragma unroll
    for (int t = 0; t < TW; ++t)
#pragma unroll
      for (int j = 0; j < NJ; ++j) acc[t][j] = (f32x4){0.f, 0.f, 0.f, 0.f};

#pragma unroll
    for (int kq = 0; kq < NKQ; ++kq) {
#pragma unroll
      for (int t = 0; t < TW; ++t) {
        const int r = t * 16 + c;                 // r & 15 == c
        const int s0 = (kq * 8 + 2 * g) ^ c;      // slot of even chunk
        const int4 v0 = *reinterpret_cast<const int4*>(lbuf + r * DIM + s0 * 16);
        const int4 v1 = *reinterpret_cast<const int4*>(lbuf + r * DIM + (s0 ^ 1) * 16);
        i32x8 av;
        av[0] = v0.x; av[1] = v0.y; av[2] = v0.z; av[3] = v0.w;
        av[4] = v1.x; av[5] = v1.y; av[6] = v1.z; av[7] = v1.w;
#pragma unroll
        for (int j = 0; j < NJ; ++j)
          acc[t][j] = __builtin_amdgcn_mfma_scale_f32_16x16x128_f8f6f4(
              av, bfr[j][kq], acc[t][j], 0, 0, 0, SCL1, 0, SCL1);
      }
    }

    // ---- epilogue: max over sub-center triples (verified), exp; lane-partial sums ----
#pragma unroll
    for (int j = 0; j < NJ; ++j) {
      float zc = 0.f;
#pragma unroll
      for (int t = 0; t < TW; ++t) {
        float s0, s1;
        if (t + 1 < TW) {
          s0 = (g == 0) ? acc[t + 1][j][0] : acc[t][j][0];
          s1 = (g == 0) ? acc[t + 1][j][1] : acc[t][j][1];
        } else {
          s0 = (g == 0) ? -2.f : acc[t][j][0];
          s1 = (g == 0) ? -2.f : acc[t][j][1];
        }
        float e0 = __shfl(s0, (lane + 16) & 63, 64);
        float e1 = __shfl(s1, (lane + 16) & 63, 64);
        const int m = (4 * t + g) % 3;
        float a0 = acc[t][j][0], a1 = acc[t][j][1], a2 = acc[t][j][2], a3 = acc[t][j][3];
        if (m == 0)      zc += eterm(fmaxf(fmaxf(a0, a1), a2)) + eterm(fmaxf(fmaxf(a3, e0), e1));
        else if (m == 1) zc += eterm(fmaxf(fmaxf(a2, a3), e0));
        else             zc += eterm(fmaxf(fmaxf(a1, a2), a3));
      }
      zreg[j] += zc;                 // lane-partial; cross-lane reduce ONCE at end
    }

    __syncthreads();   // staging drained + all waves done with cur
    cur ^= 1;
  }

  // ---- final cross-lane reduction (hoisted out of tile loop) ----
#pragma unroll
  for (int j = 0; j < NJ; ++j) {
    zreg[j] += __shfl_xor(zreg[j], 16, 64);
    zreg[j] += __shfl_xor(zreg[j], 32, 64);
  }
  if (g == 0) {
#pragma unroll
    for (int j = 0; j < NJ; ++j)
      Zp[(size_t)rg * BQ + cg * 256 + wv * 32 + j * 16 + c] = zreg[j];
  }
}

// K3: Z[b] = sum over 128 row-group partials; per-row loss; block partial sums
__global__ __launch_bounds__(256) void k_reduce(const float* __restrict__ Zp,
                                                const float* __restrict__ delta,
                                                const float* __restrict__ tl,
                                                float* __restrict__ part) {
  const int b = blockIdx.x * 256 + threadIdx.x;
  float z = 0.f;
#pragma unroll 8
  for (int nb = 0; nb < NRG; ++nb) z += Zp[(size_t)nb * BQ + b];
  float lossb = logf(z + delta[b]) - tl[b];
  __shared__ float sm[256];
  sm[threadIdx.x] = lossb;
  __syncthreads();
#pragma unroll
  for (int s = 128; s > 0; s >>= 1) {
    if (threadIdx.x < s) sm[threadIdx.x] += sm[threadIdx.x + s];
    __syncthreads();
  }
  if (threadIdx.x == 0) part[blockIdx.x] = sm[0];
}

__global__ void k_final(const float* __restrict__ part, float* __restrict__ out) {
  out[0] = (part[0] + part[1] + part[2] + part[3]) * (1.0f / BQ);
}

extern "C" void kernel_launch(void* const* d_in, const int* in_sizes, int n_in,
                              void* d_out, int out_size, void* d_ws, size_t ws_size,
                              hipStream_t stream) {
  const float* E  = (const float*)d_in[0];
  const int* lab  = (const int*)d_in[1];
  const float* W  = (const float*)d_in[2];

  char* ws = (char*)d_ws;
  unsigned char* En8 = (unsigned char*)ws;                          // 512 KB
  unsigned char* Wn8 = (unsigned char*)(ws + (size_t)BQ * DIM);     // 76.8 MB
  char* after = ws + (size_t)BQ * DIM + (size_t)NROWSW * DIM;
  float* Zp    = (float*)after;                                     // 128*1024*4 = 512 KB
  float* delta = Zp + (size_t)NRG * BQ;
  float* tl    = delta + BQ;
  float* part  = tl + BQ;

  hipLaunchKernelGGL(k_prenorm, dim3(NROWSW / 4), dim3(256), 0, stream, W, Wn8);
  hipLaunchKernelGGL(k_prep,    dim3(BQ),         dim3(64),  0, stream, E, lab, W, En8, delta, tl);
  hipLaunchKernelGGL(k_main,    dim3(NRG * NCG),  dim3(512), 0, stream, Wn8, En8, Zp);
  hipLaunchKernelGGL(k_reduce,  dim3(4),          dim3(256), 0, stream, Zp, delta, tl, part);
  hipLaunchKernelGGL(k_final,   dim3(1),          dim3(1),   0, stream, part, (float*)d_out);
}